// Round 11
// baseline (390.683 us; speedup 1.0000x reference)
//
#include <hip/hip_runtime.h>
#include <hip/hip_bf16.h>
#include <math.h>

// B=4, T=2048, D=1024, H=16, DH=64.  fp32 in / fp32 out, bf16 MFMA internal.
// out = softmax_causal((xWq)(xWk)^T / 8) (xWv) @ Wout

#define Bb 4
#define Tt 2048
#define Dd 1024
#define Hh 16
#define DH 64
#define Mrows (Bb*Tt)          // 8192
#define NEGBIG (-1.0e30f)

typedef unsigned short u16;
typedef __attribute__((ext_vector_type(8))) short bf16x8;
typedef __attribute__((ext_vector_type(4))) float f32x4;

__device__ __forceinline__ float bf2f(u16 u) {
    union { unsigned int i; float f; } v; v.i = ((unsigned int)u) << 16; return v.f;
}
__device__ __forceinline__ u16 f2bf(float f) {
    union { float f; unsigned int i; } v; v.f = f;
    unsigned int x = v.i;
    return (u16)((x + 0x7fffu + ((x >> 16) & 1u)) >> 16);      // RNE
}

__device__ __forceinline__ float exp2_(float x) {
#if __has_builtin(__builtin_amdgcn_exp2f)
    return __builtin_amdgcn_exp2f(x);      // v_exp_f32: D = 2^S0
#else
    return __expf(x * 0.69314718056f);
#endif
}

typedef __attribute__((address_space(1))) const void glob_cv;
typedef __attribute__((address_space(3))) void lds_v;
__device__ __forceinline__ void gl2lds16(const void* g, void* l) {
    __builtin_amdgcn_global_load_lds((glob_cv*)g, (lds_v*)l, 16, 0, 0);
}

// ---------------------------------------------------------------------------
// fp32 -> bf16 straight convert (x).  8 elems/thread, 16B stores.
// ---------------------------------------------------------------------------
__global__ __launch_bounds__(256) void convert_x(const float* __restrict__ src,
                                                 u16* __restrict__ dst) {
    const long i = ((long)blockIdx.x * 256 + threadIdx.x) * 8;
    float4 f0 = *(const float4*)(src + i);
    float4 f1 = *(const float4*)(src + i + 4);
    union { u16 u[8]; uint4 v; } o;
    o.u[0] = f2bf(f0.x); o.u[1] = f2bf(f0.y); o.u[2] = f2bf(f0.z); o.u[3] = f2bf(f0.w);
    o.u[4] = f2bf(f1.x); o.u[5] = f2bf(f1.y); o.u[6] = f2bf(f1.z); o.u[7] = f2bf(f1.w);
    *(uint4*)(dst + i) = o.v;
}

// ---------------------------------------------------------------------------
// fp32 W[K][N] -> bf16 Wt[N][K]  (transpose via padded LDS tile, coalesced).
// ---------------------------------------------------------------------------
__global__ __launch_bounds__(256) void convert_transpose_w(const float* __restrict__ W,
                                                           u16* __restrict__ Wt,
                                                           int N, int K) {
    __shared__ u16 tile[64][65];
    const int n0 = blockIdx.x * 64, k0 = blockIdx.y * 64;
    const int c = threadIdx.x & 63, r4 = threadIdx.x >> 6;
    #pragma unroll
    for (int p = 0; p < 16; ++p) {
        const int r = p * 4 + r4;
        tile[r][c] = f2bf(W[(size_t)(k0 + r) * N + n0 + c]);
    }
    __syncthreads();
    #pragma unroll
    for (int p = 0; p < 16; ++p) {
        const int r = p * 4 + r4;     // n index
        Wt[(size_t)(n0 + r) * K + k0 + c] = tile[c][r];
    }
}

// ---------------------------------------------------------------------------
// MFMA GEMM: C[M][N] = A[M][K] * Bt[N][K]^T, K=1024, BK=64, 128x64 tile,
// 4 waves (2m x 2n), wave-tile 64x32 = 4x2 MFMA 16x16x32 tiles.
// RATIONALE (R10 post-mortem): 4x4 wave-tile's 64 AGPR acc + 112 VGPR = 176
// unified regs -> 2 waves/SIMD, occupancy-capped at 2 blocks/CU.  4x2 tile
// halves acc to 32 AGPR -> 4 waves/SIMD, 4 blocks/CU (LDS 24KB x 4 = 96KB).
// TRANSPOSED accumulation: acc = mfma(a=B_frag, b=A_frag) -> D^T:
// lane&15 = m, quad*4+reg = n (4 consecutive n per lane -> wide stores).
// MODE 0 (N=3072): scatter Q(xlog2e/8)/K as (B,H,T,DH) via uint2; V as
// (B,H,DH,T) t-on-lanes.  MODE 1 (N=1024): fp32 out via float4.
// ---------------------------------------------------------------------------
template <int MODE>
__global__ __launch_bounds__(256, 4) void gemm_mfma(const u16* __restrict__ A,
                                                    const u16* __restrict__ Bt,
                                                    u16* __restrict__ Qo,
                                                    u16* __restrict__ Ko,
                                                    u16* __restrict__ Vo,
                                                    float* __restrict__ Out) {
    __shared__ u16 As[8 * 128 * 8];      // [kq 0..7][row 0..127][8]  16 KB
    __shared__ u16 Bs[8 * 64 * 8];       // [kq 0..7][row 0..63][8]    8 KB
    const int tid  = threadIdx.x;
    const int lane = tid & 63, w = tid >> 6;
    const int ml   = lane & 15, q = lane >> 4;
    const int wm   = w >> 1, wn = w & 1;
    const int m0 = blockIdx.y * 128, n0 = blockIdx.x * 64;

    f32x4 acc[4][2];
    #pragma unroll
    for (int i = 0; i < 4; ++i)
        #pragma unroll
        for (int j = 0; j < 2; ++j) acc[i][j] = (f32x4){0.f, 0.f, 0.f, 0.f};

    for (int k0 = 0; k0 < Dd; k0 += 64) {
        __syncthreads();
        #pragma unroll
        for (int it = 0; it < 4; ++it) {           // A: 1024 chunks
            const int c = it * 256 + tid;
            const int row = c & 127, kq = c >> 7;
            gl2lds16(A + (size_t)(m0 + row) * Dd + k0 + kq * 8, (char*)As + c * 16);
        }
        #pragma unroll
        for (int it = 0; it < 2; ++it) {           // B: 512 chunks
            const int c = it * 256 + tid;
            const int row = c & 63, kq = c >> 6;
            gl2lds16(Bt + (size_t)(n0 + row) * Dd + k0 + kq * 8, (char*)Bs + c * 16);
        }
        __syncthreads();

        #pragma unroll
        for (int ks = 0; ks < 2; ++ks) {
            const int kq = ks * 4 + q;
            bf16x8 af[4], bfr[2];
            #pragma unroll
            for (int i = 0; i < 4; ++i)
                af[i] = *(const bf16x8*)((const char*)As +
                        ((kq * 128) + wm * 64 + i * 16 + ml) * 16);
            #pragma unroll
            for (int j = 0; j < 2; ++j)
                bfr[j] = *(const bf16x8*)((const char*)Bs +
                        ((kq * 64) + wn * 32 + j * 16 + ml) * 16);
            #pragma unroll
            for (int i = 0; i < 4; ++i)
                #pragma unroll
                for (int j = 0; j < 2; ++j)
                    acc[i][j] = __builtin_amdgcn_mfma_f32_16x16x32_bf16(
                            bfr[j], af[i], acc[i][j], 0, 0, 0);   // D^T
        }
    }

    // epilogue (D^T): m = m0+wm*64+i*16+ml ; n = n0 + wn*32+j*16+q*4 + r
    if (MODE == 0) {
        const int s = n0 >> 10;                    // 0=q 1=k 2=v, block-uniform
        const int h = (n0 & 1023) >> 6;            // block-uniform head
        #pragma unroll
        for (int i = 0; i < 4; ++i) {
            const int m  = m0 + wm * 64 + i * 16 + ml;
            const int bb = m >> 11, t = m & 2047;
            const int bhn = bb * Hh + h;
            #pragma unroll
            for (int j = 0; j < 2; ++j) {
                const int dh = wn * 32 + j * 16 + q * 4;   // < 64 always
                if (s == 2) {
                    // V^T [bh][dh][t]: lanes (ml) cover consecutive t
                    #pragma unroll
                    for (int r = 0; r < 4; ++r)
                        Vo[((size_t)bhn * DH + dh + r) * Tt + t] = f2bf(acc[i][j][r]);
                } else {
                    union { u16 u[4]; uint2 v; } pk;
                    #pragma unroll
                    for (int r = 0; r < 4; ++r) {
                        float v = acc[i][j][r];
                        if (s == 0) v *= 0.125f * 1.44269504089f;  // /sqrt(DH)*log2e
                        pk.u[r] = f2bf(v);
                    }
                    u16* dst = (s == 0) ? Qo : Ko;
                    *(uint2*)(dst + ((size_t)bhn * Tt + t) * DH + dh) = pk.v;
                }
            }
        }
    } else {
        #pragma unroll
        for (int i = 0; i < 4; ++i) {
            const int m = m0 + wm * 64 + i * 16 + ml;
            #pragma unroll
            for (int j = 0; j < 2; ++j) {
                const int n = n0 + wn * 32 + j * 16 + q * 4;
                float4 st = {acc[i][j][0], acc[i][j][1], acc[i][j][2], acc[i][j][3]};
                *(float4*)(Out + (size_t)m * Dd + n) = st;
            }
        }
    }
}

// ---------------------------------------------------------------------------
// MFMA flash attention, S^T formulation, causal-pair load balancing.
// Grid (8, BH): block processes q-tiles {i, 15-i} -> exactly 17 K-iters each.
// Wave owns 32 queries (2x16); Q fragments in registers (per phase).
// ---------------------------------------------------------------------------
__global__ __launch_bounds__(256) void attn_mfma(const u16* __restrict__ Q,
                                                 const u16* __restrict__ K,
                                                 const u16* __restrict__ Vt,
                                                 u16* __restrict__ AO) {
    __shared__ u16 Ks[8 * 128 * 8];      // [dhb 0..7][key  0..127][8]   16 KB
    __shared__ u16 Vs[16 * 64 * 8];      // [kb 0..15][dh 0..63][8]      16 KB
    __shared__ u16 Ps[4][16 * 136];      // per-wave [query 16][128+8 pad] 17 KB

    const int tid  = threadIdx.x;
    const int lane = tid & 63, w = tid >> 6;
    const int nl   = lane & 15, q = lane >> 4;
    const int bh = blockIdx.y, b = bh >> 4, h = bh & 15;
    const size_t kbase = (size_t)bh * Tt * DH;
    const size_t vbase = (size_t)bh * DH * Tt;

    for (int phase = 0; phase < 2; ++phase) {
        const int qt = phase ? (15 - (int)blockIdx.x) : (int)blockIdx.x;
        const int q0 = qt * 128;

        bf16x8 qf[2][2];
        #pragma unroll
        for (int qb = 0; qb < 2; ++qb)
            #pragma unroll
            for (int s = 0; s < 2; ++s)
                qf[qb][s] = *(const bf16x8*)(Q + kbase +
                        (size_t)(q0 + w * 32 + qb * 16 + nl) * DH + (s * 4 + q) * 8);

        float m_i[2] = {NEGBIG, NEGBIG};
        float l_i[2] = {0.f, 0.f};
        f32x4 accO[2][4];
        #pragma unroll
        for (int qb = 0; qb < 2; ++qb)
            #pragma unroll
            for (int dt = 0; dt < 4; ++dt) accO[qb][dt] = (f32x4){0.f, 0.f, 0.f, 0.f};

        for (int j0 = 0; j0 <= q0; j0 += 128) {
            __syncthreads();
            #pragma unroll
            for (int it = 0; it < 4; ++it) {
                const int c = it * 256 + tid;
                gl2lds16(K + kbase + (size_t)(j0 + (c & 127)) * DH + (c >> 7) * 8,
                         (char*)Ks + c * 16);
            }
            #pragma unroll
            for (int it = 0; it < 4; ++it) {
                const int c = it * 256 + tid;
                gl2lds16(Vt + vbase + (size_t)(c & 63) * Tt + j0 + (c >> 6) * 8,
                         (char*)Vs + c * 16);
            }
            __syncthreads();

            const bool diag = (j0 == q0);

            #pragma unroll
            for (int qb = 0; qb < 2; ++qb) {
                const int qrow = w * 32 + qb * 16 + nl;

                f32x4 accst[8];
                #pragma unroll
                for (int kt = 0; kt < 8; ++kt) accst[kt] = (f32x4){0.f, 0.f, 0.f, 0.f};
                #pragma unroll
                for (int s = 0; s < 2; ++s) {
                    #pragma unroll
                    for (int kt = 0; kt < 8; ++kt) {
                        bf16x8 ak = *(const bf16x8*)((const char*)Ks +
                                ((s * 4 + q) * 128 + kt * 16 + nl) * 16);
                        accst[kt] = __builtin_amdgcn_mfma_f32_16x16x32_bf16(
                                ak, qf[qb][s], accst[kt], 0, 0, 0);
                    }
                }

                if (diag) {
                    #pragma unroll
                    for (int kt = 0; kt < 8; ++kt)
                        #pragma unroll
                        for (int r = 0; r < 4; ++r)
                            if (kt * 16 + q * 4 + r > qrow) accst[kt][r] = NEGBIG;
                }

                float mx = NEGBIG;
                #pragma unroll
                for (int kt = 0; kt < 8; ++kt) {
                    float a0 = fmaxf(accst[kt][0], accst[kt][1]);
                    float a1 = fmaxf(accst[kt][2], accst[kt][3]);
                    mx = fmaxf(mx, fmaxf(a0, a1));
                }
                mx = fmaxf(mx, __shfl_xor(mx, 16, 64));
                mx = fmaxf(mx, __shfl_xor(mx, 32, 64));
                const float nm    = fmaxf(m_i[qb], mx);
                const float alpha = exp2_(m_i[qb] - nm);
                m_i[qb] = nm;

                float rs = 0.f;
                #pragma unroll
                for (int kt = 0; kt < 8; ++kt) {
                    union { u16 u[4]; uint2 v; } pk;
                    #pragma unroll
                    for (int r = 0; r < 4; ++r) {
                        const float p = exp2_(accst[kt][r] - nm);
                        rs += p;
                        pk.u[r] = f2bf(p);
                    }
                    *(uint2*)((char*)Ps[w] + nl * 272 + kt * 32 + q * 8) = pk.v;
                }
                rs += __shfl_xor(rs, 16, 64);
                rs += __shfl_xor(rs, 32, 64);
                l_i[qb] = l_i[qb] * alpha + rs;

                #pragma unroll
                for (int dt = 0; dt < 4; ++dt)
                    #pragma unroll
                    for (int r = 0; r < 4; ++r) accO[qb][dt][r] *= alpha;

                #pragma unroll
                for (int s = 0; s < 4; ++s) {
                    bf16x8 bp = *(const bf16x8*)((const char*)Ps[w] +
                            nl * 272 + s * 64 + q * 16);
                    #pragma unroll
                    for (int dt = 0; dt < 4; ++dt) {
                        bf16x8 av = *(const bf16x8*)((const char*)Vs +
                                ((s * 4 + q) * 64 + dt * 16 + nl) * 16);
                        accO[qb][dt] = __builtin_amdgcn_mfma_f32_16x16x32_bf16(
                                av, bp, accO[qb][dt], 0, 0, 0);
                    }
                }
            }
        }

        #pragma unroll
        for (int qb = 0; qb < 2; ++qb) {
            const float inv = 1.0f / l_i[qb];
            const int t = q0 + w * 32 + qb * 16 + nl;
            #pragma unroll
            for (int dt = 0; dt < 4; ++dt) {
                union { u16 u[4]; uint2 v; } pk;
                #pragma unroll
                for (int r = 0; r < 4; ++r) pk.u[r] = f2bf(accO[qb][dt][r] * inv);
                *(uint2*)(AO + ((size_t)(b * Tt + t)) * Dd + h * DH + dt * 16 + q * 4) = pk.v;
            }
        }
    }
}

// ---------------------------------------------------------------------------
extern "C" void kernel_launch(void* const* d_in, const int* in_sizes, int n_in,
                              void* d_out, int out_size, void* d_ws, size_t ws_size,
                              hipStream_t stream) {
    const float* x_raw    = (const float*)d_in[0];
    // d_in[1] = causal mask (constant tril) — handled analytically, ignored.
    const float* Wqkv_raw = (const float*)d_in[2];
    const float* Wout_raw = (const float*)d_in[3];
    float* out = (float*)d_out;

    const size_t SZ = (size_t)Bb * Hh * Tt * DH;        // 8,388,608
    u16* ws = (u16*)d_ws;
    u16* Qw     = ws;                                   // SZ
    u16* Kw     = ws + SZ;                              // SZ
    u16* Vt     = ws + 2 * SZ;                          // SZ, [bh][dh][t]
    u16* AO     = ws + 3 * SZ;                          // SZ, (B,T,D) bf16
    u16* Wqkv_t = ws + 4 * SZ;                          // 3,145,728  [3072][1024]
    u16* Wout_t = Wqkv_t + (size_t)3 * Dd * Dd;         // 1,048,576  [1024][1024]
    u16* x_b    = (u16*)d_out;                          // x bf16 scratch in d_out

    convert_x<<<dim3(Mrows * Dd / 2048), 256, 0, stream>>>(x_raw, x_b);
    convert_transpose_w<<<dim3(3 * Dd / 64, Dd / 64), 256, 0, stream>>>(Wqkv_raw, Wqkv_t, 3 * Dd, Dd);
    convert_transpose_w<<<dim3(Dd / 64, Dd / 64),     256, 0, stream>>>(Wout_raw, Wout_t, Dd, Dd);

    gemm_mfma<0><<<dim3(3 * Dd / 64, Mrows / 128), 256, 0, stream>>>(x_b, Wqkv_t, Qw, Kw, Vt, nullptr);
    attn_mfma  <<<dim3(Tt / 256, Bb * Hh), 256, 0, stream>>>(Qw, Kw, Vt, AO);
    gemm_mfma<1><<<dim3(Dd / 64, Mrows / 128), 256, 0, stream>>>(AO, Wout_t, nullptr, nullptr, nullptr, out);
}

// Round 12
// 275.946 us; speedup vs baseline: 1.4158x; 1.4158x over previous
//
#include <hip/hip_runtime.h>
#include <hip/hip_bf16.h>
#include <math.h>

// B=4, T=2048, D=1024, H=16, DH=64.  fp32 in / fp32 out, bf16 MFMA internal.
// out = softmax_causal((xWq)(xWk)^T / 8) (xWv) @ Wout
//
// R12: "pre-tiled" dataflow.  Every producer writes the consumer's exact LDS
// image as linear 16B chunks, so every hot-loop global_load_lds reads
// CONSECUTIVE chunks (lane i -> chunk i): dense 1KB/instruction instead of a
// 64-way 2KB-strided scatter (R8-R11 evidence: all visible pipes idle ->
// address-unit request rate was the suspected limiter).

#define Bb 4
#define Tt 2048
#define Dd 1024
#define Hh 16
#define DH 64
#define Mrows (Bb*Tt)          // 8192
#define NEGBIG (-1.0e30f)
#define KB64 (Dd/64)           // 16 k-blocks per GEMM
#define CHUNKS 1024            // chunks per (128-row x 64-k) tile
#define TILEU16 8192           // u16 per tile image (1024 chunks x 8)

typedef unsigned short u16;
typedef __attribute__((ext_vector_type(8))) short bf16x8;
typedef __attribute__((ext_vector_type(4))) float f32x4;

__device__ __forceinline__ u16 f2bf(float f) {
    union { float f; unsigned int i; } v; v.f = f;
    unsigned int x = v.i;
    return (u16)((x + 0x7fffu + ((x >> 16) & 1u)) >> 16);      // RNE
}

__device__ __forceinline__ float exp2_(float x) {
#if __has_builtin(__builtin_amdgcn_exp2f)
    return __builtin_amdgcn_exp2f(x);      // v_exp_f32: D = 2^S0
#else
    return __expf(x * 0.69314718056f);
#endif
}

typedef __attribute__((address_space(1))) const void glob_cv;
typedef __attribute__((address_space(3))) void lds_v;
__device__ __forceinline__ void gl2lds16(const void* g, void* l) {
    __builtin_amdgcn_global_load_lds((glob_cv*)g, (lds_v*)l, 16, 0, 0);
}

// ---------------------------------------------------------------------------
// x fp32 (M=8192, K=1024) -> xT tiled bf16: [mb 0..63][kb 0..15][1024 chunks]
// chunk c holds x[mb*128 + (c&127)][kb*64 + (c>>7)*8 .. +8].
// ---------------------------------------------------------------------------
__global__ __launch_bounds__(256) void convert_x_tiled(const float* __restrict__ src,
                                                       u16* __restrict__ dst) {
    const int mb = blockIdx.x >> 4, kb = blockIdx.x & 15;
    const int row = threadIdx.x & 127, half = threadIdx.x >> 7;
    const float* s = src + (size_t)(mb * 128 + row) * Dd + kb * 64 + half * 32;
    u16* base = dst + (size_t)blockIdx.x * TILEU16;
    #pragma unroll
    for (int cq = 0; cq < 4; ++cq) {
        const int kq = half * 4 + cq;
        float4 f0 = *(const float4*)(s + cq * 8);
        float4 f1 = *(const float4*)(s + cq * 8 + 4);
        union { u16 u[8]; uint4 v; } o;
        o.u[0] = f2bf(f0.x); o.u[1] = f2bf(f0.y); o.u[2] = f2bf(f0.z); o.u[3] = f2bf(f0.w);
        o.u[4] = f2bf(f1.x); o.u[5] = f2bf(f1.y); o.u[6] = f2bf(f1.z); o.u[7] = f2bf(f1.w);
        *(uint4*)(base + (size_t)(kq * 128 + row) * 8) = o.v;    // coalesced
    }
}

// ---------------------------------------------------------------------------
// W fp32 [K=1024][N] -> WT tiled bf16: [nb][kb][1024 chunks];
// chunk c holds W^T[n0 + (c&127)][k0 + (c>>7)*8 .. +8].
// ---------------------------------------------------------------------------
__global__ __launch_bounds__(256) void convert_w_tiled(const float* __restrict__ W,
                                                       u16* __restrict__ Wt,
                                                       int N) {
    __shared__ u16 t[128][68];           // [n][k] +4 pad
    const int nb = blockIdx.x, kb = blockIdx.y;
    const int k0 = kb * 64, n0 = nb * 128;
    const int k = threadIdx.x >> 2, ng = threadIdx.x & 3;
    const float* s = W + (size_t)(k0 + k) * N + n0 + ng * 32;
    #pragma unroll
    for (int i = 0; i < 8; ++i) {
        float4 f = *(const float4*)(s + i * 4);
        const int n = ng * 32 + i * 4;
        t[n + 0][k] = f2bf(f.x); t[n + 1][k] = f2bf(f.y);
        t[n + 2][k] = f2bf(f.z); t[n + 3][k] = f2bf(f.w);
    }
    __syncthreads();
    u16* base = Wt + (size_t)(nb * KB64 + kb) * TILEU16;
    #pragma unroll
    for (int it = 0; it < 4; ++it) {
        const int c = it * 256 + threadIdx.x;
        const int row = c & 127, kq = c >> 7;
        union { u16 u[8]; uint4 v; } o;
        #pragma unroll
        for (int j = 0; j < 8; ++j) o.u[j] = t[row][kq * 8 + j];
        *(uint4*)(base + (size_t)c * 8) = o.v;                   // coalesced
    }
}

// ---------------------------------------------------------------------------
// MFMA GEMM on tiled operands.  128x128 tile, BK=64, single-buffer (R8 shape,
// proven best).  4 waves 2x2, wave 4x4 MFMA tiles, D^T accumulation
// (lane&15 = m, quad*4+reg = n).
// Staging: consecutive-chunk gl2lds (the whole point of this round).
// MODE 0 (N=3072): Q plain (B,H,T,DH) scaled; K -> KT tiled attn image;
//                  V -> VtT tiled attn image.  MODE 1: fp32 plain out.
// ---------------------------------------------------------------------------
template <int MODE>
__global__ __launch_bounds__(256) void gemm_mfma(const u16* __restrict__ At,
                                                 const u16* __restrict__ Bt,
                                                 u16* __restrict__ Qo,
                                                 u16* __restrict__ KT,
                                                 u16* __restrict__ VtT,
                                                 float* __restrict__ Out) {
    __shared__ u16 As[8 * 128 * 8];      // 16 KB  [kq][row][8]
    __shared__ u16 Bs[8 * 128 * 8];      // 16 KB
    const int tid  = threadIdx.x;
    const int lane = tid & 63, w = tid >> 6;
    const int ml   = lane & 15, q = lane >> 4;
    const int wm   = w >> 1, wn = w & 1;
    const int m0 = blockIdx.y * 128;

    const u16* Abase = At + (size_t)blockIdx.y * KB64 * TILEU16;
    const u16* Bbase = Bt + (size_t)blockIdx.x * KB64 * TILEU16;

    f32x4 acc[4][4];
    #pragma unroll
    for (int i = 0; i < 4; ++i)
        #pragma unroll
        for (int j = 0; j < 4; ++j) acc[i][j] = (f32x4){0.f, 0.f, 0.f, 0.f};

    for (int kb = 0; kb < KB64; ++kb) {
        __syncthreads();
        const u16* Ak = Abase + (size_t)kb * TILEU16;
        const u16* Bk = Bbase + (size_t)kb * TILEU16;
        #pragma unroll
        for (int it = 0; it < 4; ++it) {
            const int c = it * 256 + tid;
            gl2lds16(Ak + (size_t)c * 8, (char*)As + c * 16);    // dense
            gl2lds16(Bk + (size_t)c * 8, (char*)Bs + c * 16);    // dense
        }
        __syncthreads();

        #pragma unroll
        for (int ks = 0; ks < 2; ++ks) {
            const int kq = ks * 4 + q;
            bf16x8 af[4], bfr[4];
            #pragma unroll
            for (int i = 0; i < 4; ++i)
                af[i] = *(const bf16x8*)((const char*)As +
                        ((kq * 128) + wm * 64 + i * 16 + ml) * 16);
            #pragma unroll
            for (int j = 0; j < 4; ++j)
                bfr[j] = *(const bf16x8*)((const char*)Bs +
                        ((kq * 128) + wn * 64 + j * 16 + ml) * 16);
            #pragma unroll
            for (int i = 0; i < 4; ++i)
                #pragma unroll
                for (int j = 0; j < 4; ++j)
                    acc[i][j] = __builtin_amdgcn_mfma_f32_16x16x32_bf16(
                            bfr[j], af[i], acc[i][j], 0, 0, 0);   // D^T
        }
    }

    // epilogue (D^T): m = m0+wm*64+i*16+ml ; n-local = wn*64 + j*16 + q*4 + r
    if (MODE == 0) {
        const int s  = (blockIdx.x * 128) >> 10;       // 0=q 1=k 2=v, uniform
        const int h0 = ((blockIdx.x * 128) & 1023) >> 6;
        #pragma unroll
        for (int i = 0; i < 4; ++i) {
            const int m  = m0 + wm * 64 + i * 16 + ml;
            const int bb = m >> 11, t = m & 2047;
            const int bhn = bb * Hh + h0 + wn;         // wn folds into head
            #pragma unroll
            for (int j = 0; j < 4; ++j) {
                const int dh = j * 16 + q * 4;         // + r, < 64
                if (s == 2) {
                    // VtT image: [bh][jb][kb2*64 + dh][t&7]
                    u16* vb = VtT + (size_t)(bhn * 16 + (t >> 7)) * TILEU16;
                    #pragma unroll
                    for (int r = 0; r < 4; ++r)
                        vb[(size_t)(((t >> 3) & 15) * 64 + dh + r) * 8 + (t & 7)]
                            = f2bf(acc[i][j][r]);
                } else if (s == 1) {
                    // KT image: [bh][jb][(dh>>3)*128 + (t&127)][dh&7]
                    union { u16 u[4]; uint2 v; } pk;
                    #pragma unroll
                    for (int r = 0; r < 4; ++r) pk.u[r] = f2bf(acc[i][j][r]);
                    *(uint2*)(KT + (size_t)(bhn * 16 + (t >> 7)) * TILEU16 +
                              (size_t)((j * 2 + (q >> 1)) * 128 + (t & 127)) * 8 +
                              (q & 1) * 4) = pk.v;
                } else {
                    union { u16 u[4]; uint2 v; } pk;
                    #pragma unroll
                    for (int r = 0; r < 4; ++r)
                        pk.u[r] = f2bf(acc[i][j][r] * (0.125f * 1.44269504089f));
                    *(uint2*)(Qo + ((size_t)bhn * Tt + t) * DH + dh) = pk.v;
                }
            }
        }
    } else {
        #pragma unroll
        for (int i = 0; i < 4; ++i) {
            const int m = m0 + wm * 64 + i * 16 + ml;
            #pragma unroll
            for (int j = 0; j < 4; ++j) {
                const int n = blockIdx.x * 128 + wn * 64 + j * 16 + q * 4;
                float4 st = {acc[i][j][0], acc[i][j][1], acc[i][j][2], acc[i][j][3]};
                *(float4*)(Out + (size_t)m * Dd + n) = st;
            }
        }
    }
}

// ---------------------------------------------------------------------------
// MFMA flash attention, S^T formulation, causal-pair balancing (R7/R8 best).
// Staging now reads tiled KT/VtT images with consecutive-chunk gl2lds.
// Epilogue writes AOT = gemm1's tiled A image.
// ---------------------------------------------------------------------------
__global__ __launch_bounds__(256) void attn_mfma(const u16* __restrict__ Q,
                                                 const u16* __restrict__ KT,
                                                 const u16* __restrict__ VtT,
                                                 u16* __restrict__ AOT) {
    __shared__ u16 Ks[8 * 128 * 8];      // [dhb][key][8]  16 KB
    __shared__ u16 Vs[16 * 64 * 8];      // [kb][dh][8]    16 KB
    __shared__ u16 Ps[4][16 * 136];      // per-wave P     17 KB

    const int tid  = threadIdx.x;
    const int lane = tid & 63, w = tid >> 6;
    const int nl   = lane & 15, q = lane >> 4;
    const int bh = blockIdx.y, b = bh >> 4, h = bh & 15;
    const size_t kbase = (size_t)bh * Tt * DH;

    for (int phase = 0; phase < 2; ++phase) {
        const int qt = phase ? (15 - (int)blockIdx.x) : (int)blockIdx.x;
        const int q0 = qt * 128;

        bf16x8 qf[2][2];
        #pragma unroll
        for (int qb = 0; qb < 2; ++qb)
            #pragma unroll
            for (int s = 0; s < 2; ++s)
                qf[qb][s] = *(const bf16x8*)(Q + kbase +
                        (size_t)(q0 + w * 32 + qb * 16 + nl) * DH + (s * 4 + q) * 8);

        float m_i[2] = {NEGBIG, NEGBIG};
        float l_i[2] = {0.f, 0.f};
        f32x4 accO[2][4];
        #pragma unroll
        for (int qb = 0; qb < 2; ++qb)
            #pragma unroll
            for (int dt = 0; dt < 4; ++dt) accO[qb][dt] = (f32x4){0.f, 0.f, 0.f, 0.f};

        for (int j0 = 0; j0 <= q0; j0 += 128) {
            __syncthreads();
            const u16* Kb = KT  + (size_t)(bh * 16 + (j0 >> 7)) * TILEU16;
            const u16* Vb = VtT + (size_t)(bh * 16 + (j0 >> 7)) * TILEU16;
            #pragma unroll
            for (int it = 0; it < 4; ++it) {
                const int c = it * 256 + tid;
                gl2lds16(Kb + (size_t)c * 8, (char*)Ks + c * 16);  // dense
                gl2lds16(Vb + (size_t)c * 8, (char*)Vs + c * 16);  // dense
            }
            __syncthreads();

            const bool diag = (j0 == q0);

            #pragma unroll
            for (int qb = 0; qb < 2; ++qb) {
                const int qrow = w * 32 + qb * 16 + nl;

                f32x4 accst[8];
                #pragma unroll
                for (int kt = 0; kt < 8; ++kt) accst[kt] = (f32x4){0.f, 0.f, 0.f, 0.f};
                #pragma unroll
                for (int s = 0; s < 2; ++s) {
                    #pragma unroll
                    for (int kt = 0; kt < 8; ++kt) {
                        bf16x8 ak = *(const bf16x8*)((const char*)Ks +
                                ((s * 4 + q) * 128 + kt * 16 + nl) * 16);
                        accst[kt] = __builtin_amdgcn_mfma_f32_16x16x32_bf16(
                                ak, qf[qb][s], accst[kt], 0, 0, 0);
                    }
                }

                if (diag) {
                    #pragma unroll
                    for (int kt = 0; kt < 8; ++kt)
                        #pragma unroll
                        for (int r = 0; r < 4; ++r)
                            if (kt * 16 + q * 4 + r > qrow) accst[kt][r] = NEGBIG;
                }

                float mx = NEGBIG;
                #pragma unroll
                for (int kt = 0; kt < 8; ++kt) {
                    float a0 = fmaxf(accst[kt][0], accst[kt][1]);
                    float a1 = fmaxf(accst[kt][2], accst[kt][3]);
                    mx = fmaxf(mx, fmaxf(a0, a1));
                }
                mx = fmaxf(mx, __shfl_xor(mx, 16, 64));
                mx = fmaxf(mx, __shfl_xor(mx, 32, 64));
                const float nm    = fmaxf(m_i[qb], mx);
                const float alpha = exp2_(m_i[qb] - nm);
                m_i[qb] = nm;

                float rs = 0.f;
                #pragma unroll
                for (int kt = 0; kt < 8; ++kt) {
                    union { u16 u[4]; uint2 v; } pk;
                    #pragma unroll
                    for (int r = 0; r < 4; ++r) {
                        const float p = exp2_(accst[kt][r] - nm);
                        rs += p;
                        pk.u[r] = f2bf(p);
                    }
                    *(uint2*)((char*)Ps[w] + nl * 272 + kt * 32 + q * 8) = pk.v;
                }
                rs += __shfl_xor(rs, 16, 64);
                rs += __shfl_xor(rs, 32, 64);
                l_i[qb] = l_i[qb] * alpha + rs;

                #pragma unroll
                for (int dt = 0; dt < 4; ++dt)
                    #pragma unroll
                    for (int r = 0; r < 4; ++r) accO[qb][dt][r] *= alpha;

                #pragma unroll
                for (int s = 0; s < 4; ++s) {
                    bf16x8 bp = *(const bf16x8*)((const char*)Ps[w] +
                            nl * 272 + s * 64 + q * 16);
                    #pragma unroll
                    for (int dt = 0; dt < 4; ++dt) {
                        bf16x8 av = *(const bf16x8*)((const char*)Vs +
                                ((s * 4 + q) * 64 + dt * 16 + nl) * 16);
                        accO[qb][dt] = __builtin_amdgcn_mfma_f32_16x16x32_bf16(
                                av, bp, accO[qb][dt], 0, 0, 0);
                    }
                }
            }
        }

        // epilogue -> AOT (gemm1 tiled A image): m = b*2048 + t (global row),
        // k = h*64 + dh'; chunk = (dh'>>3)*128 + (m&127); off = dh'&7.
        #pragma unroll
        for (int qb = 0; qb < 2; ++qb) {
            const float inv = 1.0f / l_i[qb];
            const int t = q0 + w * 32 + qb * 16 + nl;
            const int m = b * Tt + t;
            u16* ab = AOT + (size_t)((m >> 7) * KB64 + h) * TILEU16;
            #pragma unroll
            for (int dt = 0; dt < 4; ++dt) {
                union { u16 u[4]; uint2 v; } pk;
                #pragma unroll
                for (int r = 0; r < 4; ++r) pk.u[r] = f2bf(accO[qb][dt][r] * inv);
                *(uint2*)(ab + (size_t)((dt * 2 + (q >> 1)) * 128 + (m & 127)) * 8 +
                          (q & 1) * 4) = pk.v;
            }
        }
    }
}

// ---------------------------------------------------------------------------
extern "C" void kernel_launch(void* const* d_in, const int* in_sizes, int n_in,
                              void* d_out, int out_size, void* d_ws, size_t ws_size,
                              hipStream_t stream) {
    const float* x_raw    = (const float*)d_in[0];
    // d_in[1] = causal mask (constant tril) — handled analytically, ignored.
    const float* Wqkv_raw = (const float*)d_in[2];
    const float* Wout_raw = (const float*)d_in[3];
    float* out = (float*)d_out;

    const size_t SZ = (size_t)Bb * Hh * Tt * DH;        // 8,388,608
    u16* ws = (u16*)d_ws;
    u16* Qw     = ws;                                   // SZ, plain (B,H,T,DH)
    u16* KT     = ws + SZ;                              // SZ, tiled [bh][jb][chunks]
    u16* VtT    = ws + 2 * SZ;                          // SZ, tiled [bh][jb][chunks]
    u16* AOT    = ws + 3 * SZ;                          // SZ, tiled [mb][kb][chunks]
    u16* WqkvT  = ws + 4 * SZ;                          // 3,145,728 tiled
    u16* WoutT  = WqkvT + (size_t)3 * Dd * Dd;          // 1,048,576 tiled
    u16* xT     = (u16*)d_out;                          // 16.8MB tiled, in d_out

    convert_x_tiled<<<dim3(64 * KB64), 256, 0, stream>>>(x_raw, xT);
    convert_w_tiled<<<dim3(3 * Dd / 128, KB64), 256, 0, stream>>>(Wqkv_raw, WqkvT, 3 * Dd);
    convert_w_tiled<<<dim3(Dd / 128, KB64),     256, 0, stream>>>(Wout_raw, WoutT, Dd);

    gemm_mfma<0><<<dim3(3 * Dd / 128, Mrows / 128), 256, 0, stream>>>(xT, WqkvT, Qw, KT, VtT, nullptr);
    attn_mfma  <<<dim3(Tt / 256, Bb * Hh), 256, 0, stream>>>(Qw, KT, VtT, AOT);
    gemm_mfma<1><<<dim3(Dd / 128, Mrows / 128), 256, 0, stream>>>(AOT, WoutT, nullptr, nullptr, nullptr, out);
}